// Round 3
// baseline (434.396 us; speedup 1.0000x reference)
//
#include <hip/hip_runtime.h>

// LIF dual forward: x [T,B,N,C] f32, decay scalar.
// out = concat(spikes [T,B,N,C] f32, vpool [T,B,C] f32) flat.
//
// Stage 1: one thread owns (b, 2 n-rows, 4 channels); t-loop unrolled in regs.
//          Block (64x7 threads) covers 14 n-rows x 64 c4; LDS-reduces over ty
//          and stores per-chunk partial sums (plain stores) to d_ws.
// Stage 2: sums the 14 partial chunks -> vpool. No atomics anywhere.
constexpr int T   = 16;
constexpr int B   = 32;
constexpr int N   = 196;
constexpr int C   = 512;
constexpr int C4  = C / 4;     // 128 float4 columns
constexpr int TX  = 64;        // c4 lanes per block
constexpr int TY  = 7;         // n-groups per block
constexpr int RPT = 2;         // rows per thread
constexpr int ROWS_PER_BLOCK = TY * RPT;          // 14
constexpr int NCHUNK = N / ROWS_PER_BLOCK;        // 14
constexpr int CCHUNK = C4 / TX;                   // 2
constexpr int PCHUNK_F4 = T * B * C4;             // float4 per partial chunk = 65536

typedef float f32x4 __attribute__((ext_vector_type(4)));

__global__ __launch_bounds__(TX * TY) void lif_stage1(
    const float4* __restrict__ x,
    const float*  __restrict__ decay,
    float4* __restrict__ spikes,
    float4* __restrict__ partial) {         // [NCHUNK][T][B][C4] float4
  __shared__ float4 red[TY][4][TX];         // 28 KB, 4 rounds of 4 t

  const int tx = threadIdx.x;               // 0..63
  const int ty = threadIdx.y;               // 0..6
  const int cc = blockIdx.x;                // 0..1
  const int nc = blockIdx.y;                // 0..13
  const int b  = blockIdx.z;                // 0..31

  const int c4 = cc * TX + tx;              // 0..127
  const float d = decay[0];

  float4 vpsum[T];
#pragma unroll
  for (int t = 0; t < T; ++t) vpsum[t] = make_float4(0.f, 0.f, 0.f, 0.f);

  const size_t tstride = (size_t)B * N * C4;   // float4 units

#pragma unroll
  for (int r = 0; r < RPT; ++r) {
    const int n = nc * ROWS_PER_BLOCK + ty * RPT + r;
    size_t idx = ((size_t)b * N + n) * C4 + c4;
    float4 v = make_float4(0.f, 0.f, 0.f, 0.f);

#pragma unroll
    for (int t = 0; t < T; ++t) {
      float4 xt = x[idx];

      v.x = d * v.x + xt.x;
      v.y = d * v.y + xt.y;
      v.z = d * v.z + xt.z;
      v.w = d * v.w + xt.w;

      vpsum[t].x += v.x;
      vpsum[t].y += v.y;
      vpsum[t].z += v.z;
      vpsum[t].w += v.w;

      f32x4 s;
      s.x = (v.x >= 1.0f) ? 1.0f : 0.0f;  v.x = (v.x >= 1.0f) ? 0.0f : v.x;
      s.y = (v.y >= 1.0f) ? 1.0f : 0.0f;  v.y = (v.y >= 1.0f) ? 0.0f : v.y;
      s.z = (v.z >= 1.0f) ? 1.0f : 0.0f;  v.z = (v.z >= 1.0f) ? 0.0f : v.z;
      s.w = (v.w >= 1.0f) ? 1.0f : 0.0f;  v.w = (v.w >= 1.0f) ? 0.0f : v.w;

      // spikes are write-once, never re-read: non-temporal keeps x resident in L3
      __builtin_nontemporal_store(s, (f32x4*)&spikes[idx]);
      idx += tstride;
    }
  }

  // Reduce vpsum over the 7 ty groups via LDS, 4 t per round; plain stores.
  const int flat = ty * TX + tx;            // 0..447
#pragma unroll 1
  for (int tc = 0; tc < T; tc += 4) {
#pragma unroll
    for (int j = 0; j < 4; ++j) red[ty][j][tx] = vpsum[tc + j];
    __syncthreads();
    if (flat < 4 * TX) {
      const int j   = flat >> 6;            // 0..3
      const int col = flat & 63;            // 0..63
      float4 a = red[0][j][col];
#pragma unroll
      for (int k = 1; k < TY; ++k) {
        float4 r2 = red[k][j][col];
        a.x += r2.x; a.y += r2.y; a.z += r2.z; a.w += r2.w;
      }
      const int t = tc + j;
      const size_t pidx = (size_t)nc * PCHUNK_F4 +
                          ((size_t)t * B + b) * C4 + (cc * TX + col);
      partial[pidx] = a;
    }
    __syncthreads();
  }
}

__global__ __launch_bounds__(256) void lif_stage2(
    const float4* __restrict__ partial,     // [NCHUNK][T*B*C4] float4
    float4* __restrict__ vpool) {           // [T*B*C4] float4
  const int gid = blockIdx.x * 256 + threadIdx.x;   // 0..65535
  const float inv_n = 1.0f / (float)N;
  float4 a = partial[gid];
#pragma unroll
  for (int k = 1; k < NCHUNK; ++k) {
    float4 r = partial[(size_t)k * PCHUNK_F4 + gid];
    a.x += r.x; a.y += r.y; a.z += r.z; a.w += r.w;
  }
  a.x *= inv_n; a.y *= inv_n; a.z *= inv_n; a.w *= inv_n;
  vpool[gid] = a;
}

extern "C" void kernel_launch(void* const* d_in, const int* in_sizes, int n_in,
                              void* d_out, int out_size, void* d_ws, size_t ws_size,
                              hipStream_t stream) {
  const float4* x     = (const float4*)d_in[0];
  const float*  decay = (const float*)d_in[1];

  float* out = (float*)d_out;
  const size_t spike_elems = (size_t)T * B * N * C;   // 51,380,224

  float4* spikes  = (float4*)out;
  float4* vpool   = (float4*)(out + spike_elems);
  float4* partial = (float4*)d_ws;   // needs NCHUNK*T*B*C floats = 14.7 MB

  dim3 block1(TX, TY);                     // 64 x 7 = 448 threads (7 waves)
  dim3 grid1(CCHUNK, NCHUNK, B);           // 2 x 14 x 32 = 896 blocks
  lif_stage1<<<grid1, block1, 0, stream>>>(x, decay, spikes, partial);

  lif_stage2<<<dim3(PCHUNK_F4 / 256), dim3(256), 0, stream>>>(partial, vpool);
}

// Round 4
// 432.643 us; speedup vs baseline: 1.0041x; 1.0041x over previous
//
#include <hip/hip_runtime.h>

// LIF dual forward: x [T,B,N,C] f32, decay scalar.
// out = concat(spikes [T,B,N,C] f32, vpool [T,B,C] f32) flat.
//
// Stage 1: one thread owns (b, 2 n-rows, 4 channels); t-loop unrolled in regs.
//          Block (64x7 threads) covers 14 n-rows x 64 c4; LDS-reduces over ty
//          and stores per-chunk partial sums (plain stores) to d_ws.
// Stage 2: sums the 14 partial chunks -> vpool. No atomics anywhere.
// R4: plain spike stores (R3's nontemporal stores caused ~2.4x HBM write
//     amplification: WRITE_SIZE 286->485 MB. Let L2 write-combine.)
constexpr int T   = 16;
constexpr int B   = 32;
constexpr int N   = 196;
constexpr int C   = 512;
constexpr int C4  = C / 4;     // 128 float4 columns
constexpr int TX  = 64;        // c4 lanes per block
constexpr int TY  = 7;         // n-groups per block
constexpr int RPT = 2;         // rows per thread
constexpr int ROWS_PER_BLOCK = TY * RPT;          // 14
constexpr int NCHUNK = N / ROWS_PER_BLOCK;        // 14
constexpr int CCHUNK = C4 / TX;                   // 2
constexpr int PCHUNK_F4 = T * B * C4;             // float4 per partial chunk = 65536

__global__ __launch_bounds__(TX * TY) void lif_stage1(
    const float4* __restrict__ x,
    const float*  __restrict__ decay,
    float4* __restrict__ spikes,
    float4* __restrict__ partial) {         // [NCHUNK][T][B][C4] float4
  __shared__ float4 red[TY][4][TX];         // 28 KB, 4 rounds of 4 t

  const int tx = threadIdx.x;               // 0..63
  const int ty = threadIdx.y;               // 0..6
  const int cc = blockIdx.x;                // 0..1
  const int nc = blockIdx.y;                // 0..13
  const int b  = blockIdx.z;                // 0..31

  const int c4 = cc * TX + tx;              // 0..127
  const float d = decay[0];

  float4 vpsum[T];
#pragma unroll
  for (int t = 0; t < T; ++t) vpsum[t] = make_float4(0.f, 0.f, 0.f, 0.f);

  const size_t tstride = (size_t)B * N * C4;   // float4 units

#pragma unroll
  for (int r = 0; r < RPT; ++r) {
    const int n = nc * ROWS_PER_BLOCK + ty * RPT + r;
    size_t idx = ((size_t)b * N + n) * C4 + c4;
    float4 v = make_float4(0.f, 0.f, 0.f, 0.f);

#pragma unroll
    for (int t = 0; t < T; ++t) {
      float4 xt = x[idx];

      v.x = d * v.x + xt.x;
      v.y = d * v.y + xt.y;
      v.z = d * v.z + xt.z;
      v.w = d * v.w + xt.w;

      vpsum[t].x += v.x;
      vpsum[t].y += v.y;
      vpsum[t].z += v.z;
      vpsum[t].w += v.w;

      float4 s;
      s.x = (v.x >= 1.0f) ? 1.0f : 0.0f;  v.x = (v.x >= 1.0f) ? 0.0f : v.x;
      s.y = (v.y >= 1.0f) ? 1.0f : 0.0f;  v.y = (v.y >= 1.0f) ? 0.0f : v.y;
      s.z = (v.z >= 1.0f) ? 1.0f : 0.0f;  v.z = (v.z >= 1.0f) ? 0.0f : v.z;
      s.w = (v.w >= 1.0f) ? 1.0f : 0.0f;  v.w = (v.w >= 1.0f) ? 0.0f : v.w;

      spikes[idx] = s;
      idx += tstride;
    }
  }

  // Reduce vpsum over the 7 ty groups via LDS, 4 t per round; plain stores.
  const int flat = ty * TX + tx;            // 0..447
#pragma unroll 1
  for (int tc = 0; tc < T; tc += 4) {
#pragma unroll
    for (int j = 0; j < 4; ++j) red[ty][j][tx] = vpsum[tc + j];
    __syncthreads();
    if (flat < 4 * TX) {
      const int j   = flat >> 6;            // 0..3
      const int col = flat & 63;            // 0..63
      float4 a = red[0][j][col];
#pragma unroll
      for (int k = 1; k < TY; ++k) {
        float4 r2 = red[k][j][col];
        a.x += r2.x; a.y += r2.y; a.z += r2.z; a.w += r2.w;
      }
      const int t = tc + j;
      const size_t pidx = (size_t)nc * PCHUNK_F4 +
                          ((size_t)t * B + b) * C4 + (cc * TX + col);
      partial[pidx] = a;
    }
    __syncthreads();
  }
}

__global__ __launch_bounds__(256) void lif_stage2(
    const float4* __restrict__ partial,     // [NCHUNK][T*B*C4] float4
    float4* __restrict__ vpool) {           // [T*B*C4] float4
  const int gid = blockIdx.x * 256 + threadIdx.x;   // 0..65535
  const float inv_n = 1.0f / (float)N;
  float4 a = partial[gid];
#pragma unroll
  for (int k = 1; k < NCHUNK; ++k) {
    float4 r = partial[(size_t)k * PCHUNK_F4 + gid];
    a.x += r.x; a.y += r.y; a.z += r.z; a.w += r.w;
  }
  a.x *= inv_n; a.y *= inv_n; a.z *= inv_n; a.w *= inv_n;
  vpool[gid] = a;
}

extern "C" void kernel_launch(void* const* d_in, const int* in_sizes, int n_in,
                              void* d_out, int out_size, void* d_ws, size_t ws_size,
                              hipStream_t stream) {
  const float4* x     = (const float4*)d_in[0];
  const float*  decay = (const float*)d_in[1];

  float* out = (float*)d_out;
  const size_t spike_elems = (size_t)T * B * N * C;   // 51,380,224

  float4* spikes  = (float4*)out;
  float4* vpool   = (float4*)(out + spike_elems);
  float4* partial = (float4*)d_ws;   // needs NCHUNK*T*B*C floats = 14.7 MB

  dim3 block1(TX, TY);                     // 64 x 7 = 448 threads (7 waves)
  dim3 grid1(CCHUNK, NCHUNK, B);           // 2 x 14 x 32 = 896 blocks
  lif_stage1<<<grid1, block1, 0, stream>>>(x, decay, spikes, partial);

  lif_stage2<<<dim3(PCHUNK_F4 / 256), dim3(256), 0, stream>>>(partial, vpool);
}

// Round 5
// 377.057 us; speedup vs baseline: 1.1521x; 1.1474x over previous
//
#include <hip/hip_runtime.h>

// LIF dual forward: x [T,B,N,C] f32, decay scalar.
// out = concat(spikes [T,B,N,C] f32, vpool [T,B,C] f32) flat.
//
// Stage 1: one thread owns (b, 2 n-rows, 4 channels); t-loop unrolled in regs.
//          Block (64x7) covers 14 n-rows x 64 c4; LDS-reduces over ty, stores
//          per-chunk partials to d_ws. Stage 2 sums 14 chunks -> vpool.
// R5: x loads are NON-TEMPORAL. The harness poisons d_out (257 MB) into L3
//     right before launch; R4's x stream evicted those dirty lines to HBM
//     before our spike stores could overwrite them (WRITE_SIZE 500 MB =
//     196 spikes + ~257 poison drain + partials). nt x-loads don't allocate
//     in L3 -> poison lines absorbed by our stores in-cache.
constexpr int T   = 16;
constexpr int B   = 32;
constexpr int N   = 196;
constexpr int C   = 512;
constexpr int C4  = C / 4;     // 128 float4 columns
constexpr int TX  = 64;        // c4 lanes per block
constexpr int TY  = 7;         // n-groups per block
constexpr int RPT = 2;         // rows per thread
constexpr int ROWS_PER_BLOCK = TY * RPT;          // 14
constexpr int NCHUNK = N / ROWS_PER_BLOCK;        // 14
constexpr int CCHUNK = C4 / TX;                   // 2
constexpr int PCHUNK_F4 = T * B * C4;             // float4 per partial chunk = 65536

typedef float f32x4 __attribute__((ext_vector_type(4)));

__global__ __launch_bounds__(TX * TY, 2) void lif_stage1(
    const f32x4* __restrict__ x,
    const float* __restrict__ decay,
    f32x4* __restrict__ spikes,
    f32x4* __restrict__ partial) {          // [NCHUNK][T][B][C4] f32x4
  __shared__ f32x4 red[TY][4][TX];          // 28 KB, 4 rounds of 4 t

  const int tx = threadIdx.x;               // 0..63
  const int ty = threadIdx.y;               // 0..6
  const int cc = blockIdx.x;                // 0..1
  const int nc = blockIdx.y;                // 0..13
  const int b  = blockIdx.z;                // 0..31

  const int c4 = cc * TX + tx;              // 0..127
  const float d = decay[0];

  f32x4 vpsum[T];
#pragma unroll
  for (int t = 0; t < T; ++t) vpsum[t] = (f32x4)(0.f);

  const size_t tstride = (size_t)B * N * C4;   // f32x4 units

#pragma unroll
  for (int r = 0; r < RPT; ++r) {
    const int n = nc * ROWS_PER_BLOCK + ty * RPT + r;
    size_t idx = ((size_t)b * N + n) * C4 + c4;
    f32x4 v = (f32x4)(0.f);

#pragma unroll
    for (int t = 0; t < T; ++t) {
      // x is read exactly once per launch: non-temporal (don't pollute L3,
      // keep poisoned d_out lines resident for our stores to absorb).
      f32x4 xt = __builtin_nontemporal_load(&x[idx]);

      v.x = d * v.x + xt.x;
      v.y = d * v.y + xt.y;
      v.z = d * v.z + xt.z;
      v.w = d * v.w + xt.w;

      vpsum[t].x += v.x;
      vpsum[t].y += v.y;
      vpsum[t].z += v.z;
      vpsum[t].w += v.w;

      f32x4 s;
      s.x = (v.x >= 1.0f) ? 1.0f : 0.0f;  v.x = (v.x >= 1.0f) ? 0.0f : v.x;
      s.y = (v.y >= 1.0f) ? 1.0f : 0.0f;  v.y = (v.y >= 1.0f) ? 0.0f : v.y;
      s.z = (v.z >= 1.0f) ? 1.0f : 0.0f;  v.z = (v.z >= 1.0f) ? 0.0f : v.z;
      s.w = (v.w >= 1.0f) ? 1.0f : 0.0f;  v.w = (v.w >= 1.0f) ? 0.0f : v.w;

      spikes[idx] = s;   // plain store: overwrite poisoned line in L2/L3
      idx += tstride;
    }
  }

  // Reduce vpsum over the 7 ty groups via LDS, 4 t per round; plain stores.
  const int flat = ty * TX + tx;            // 0..447
#pragma unroll 1
  for (int tc = 0; tc < T; tc += 4) {
#pragma unroll
    for (int j = 0; j < 4; ++j) red[ty][j][tx] = vpsum[tc + j];
    __syncthreads();
    if (flat < 4 * TX) {
      const int j   = flat >> 6;            // 0..3
      const int col = flat & 63;            // 0..63
      f32x4 a = red[0][j][col];
#pragma unroll
      for (int k = 1; k < TY; ++k) {
        f32x4 r2 = red[k][j][col];
        a.x += r2.x; a.y += r2.y; a.z += r2.z; a.w += r2.w;
      }
      const int t = tc + j;
      const size_t pidx = (size_t)nc * PCHUNK_F4 +
                          ((size_t)t * B + b) * C4 + (cc * TX + col);
      partial[pidx] = a;
    }
    __syncthreads();
  }
}

__global__ __launch_bounds__(256) void lif_stage2(
    const f32x4* __restrict__ partial,      // [NCHUNK][T*B*C4] f32x4
    f32x4* __restrict__ vpool) {            // [T*B*C4] f32x4
  const int gid = blockIdx.x * 256 + threadIdx.x;   // 0..65535
  const float inv_n = 1.0f / (float)N;
  f32x4 a = partial[gid];
#pragma unroll
  for (int k = 1; k < NCHUNK; ++k) {
    f32x4 r = partial[(size_t)k * PCHUNK_F4 + gid];
    a.x += r.x; a.y += r.y; a.z += r.z; a.w += r.w;
  }
  a.x *= inv_n; a.y *= inv_n; a.z *= inv_n; a.w *= inv_n;
  vpool[gid] = a;
}

extern "C" void kernel_launch(void* const* d_in, const int* in_sizes, int n_in,
                              void* d_out, int out_size, void* d_ws, size_t ws_size,
                              hipStream_t stream) {
  const f32x4* x      = (const f32x4*)d_in[0];
  const float* decay  = (const float*)d_in[1];

  float* out = (float*)d_out;
  const size_t spike_elems = (size_t)T * B * N * C;   // 51,380,224

  f32x4* spikes  = (f32x4*)out;
  f32x4* vpool   = (f32x4*)(out + spike_elems);
  f32x4* partial = (f32x4*)d_ws;   // needs NCHUNK*T*B*C floats = 14.7 MB

  dim3 block1(TX, TY);                     // 64 x 7 = 448 threads (7 waves)
  dim3 grid1(CCHUNK, NCHUNK, B);           // 2 x 14 x 32 = 896 blocks
  lif_stage1<<<grid1, block1, 0, stream>>>(x, decay, spikes, partial);

  lif_stage2<<<dim3(PCHUNK_F4 / 256), dim3(256), 0, stream>>>(partial, vpool);
}